// Round 10
// baseline (124.505 us; speedup 1.0000x reference)
//
#include <hip/hip_runtime.h>
#include <math.h>

// AetherSparcNet round 10 — R8 two-kernel structure (best: 90.4us) with:
//  kT: shfl->DPP (VALU pipe, zero ds-pipe) + no LDS (W2 from L1/L2, 4-way
//      wave-broadcast dedup). R8's kT was ds-pipe bound: 524k ds_swizzle
//      wave-instrs (4 shfl/j/wave) + 64KB LDS staging at 2 blocks/CU.
//      DPP reduction: merge dual-entry via row_ror:8, then directional sum
//      row_shr:1/2/4 -> full sums at p==7 (e0) and p==15 (e1).
//  kS: R8 scan/lookback/epilogue verbatim; n_active via 16 banked agent
//      fetch_adds + ACQ_REL ticket (poison-bias arithmetic: banks start
//      0xAAAAAAAA, subtract 16 poisons). Last block writes out[n]. Removes
//      block-0's serial 2048-slot spin-gather tail.
// R9 lesson (51us kF): never let thousands of blocks poll agent-scope
// mailboxes or chain agent-bypass loads — coherence-point contention.

#define THRESH   0.045f
#define NH       128
#define TSZ      8192
#define GMIN     -6.0f
#define GMAX     6.0f
#define TPB      256
#define ITEMS    2
#define CHUNK    (TPB * ITEMS)   // 512
#define NSCAN    2048            // 1M / 512
#define NTBLK    256             // kT blocks, 32 entries each
#define POISON32 0xAAAAAAAAu

#define ROW_SHR1 0x111
#define ROW_SHR2 0x112
#define ROW_SHR4 0x114
#define ROW_ROR8 0x128

// u + dpp_perm(v): DPP runs on the VALU pipe (not LDS like ds_swizzle).
#define DPP_ADD(u, v, ctrl)                                                  \
  ((u) + __builtin_bit_cast(float, __builtin_amdgcn_update_dpp(              \
             0, __builtin_bit_cast(int, (v)), (ctrl), 0xf, 0xf, true)))

// ---------------- kT: table build (no LDS, DPP reduction) ----------------
__global__ __launch_bounds__(TPB) void kT(const float* __restrict__ W1,
                                          const float* __restrict__ b1,
                                          const float* __restrict__ W2,
                                          const float* __restrict__ b2,
                                          const float* __restrict__ W3,
                                          const float* __restrict__ b3,
                                          float* __restrict__ table) {
  const int t = threadIdx.x, b = blockIdx.x;
  const int p  = t & 15;                  // lane in 16-lane DPP row
  const int e0 = b * 32 + (t >> 4) * 2;   // 16 groups x 2 entries
  const float step = (GMAX - GMIN) * (1.0f / (float)(TSZ - 1));
  const float xv0 = GMIN + step * (float)e0;
  const float xv1 = xv0 + step;

  // lane p owns k in {4*(p+16c)+r : c<2, r<4}
  float h10[8], h11[8];
  #pragma unroll
  for (int c = 0; c < 2; ++c) {
    #pragma unroll
    for (int r = 0; r < 4; ++r) {
      const int k = 4 * (p + 16 * c) + r;
      const float w = W1[k], bb = b1[k];
      h10[c * 4 + r] = fmaxf(fmaf(xv0, w, bb), 0.0f);
      h11[c * 4 + r] = fmaxf(fmaf(xv1, w, bb), 0.0f);
    }
  }
  const bool hi = (p & 8) != 0;
  float y = 0.0f;                 // valid at p==7 (e0) and p==15 (e1)
  const float b3v = b3[0];
  #pragma unroll 4
  for (int j = 0; j < NH; ++j) {
    const float* row = &W2[j * NH];
    float a0 = 0.f, a1 = 0.f, c0 = 0.f, c1 = 0.f;
    #pragma unroll
    for (int c = 0; c < 2; ++c) {
      const float4 w = *(const float4*)&row[4 * (p + 16 * c)];
      a0 = fmaf(h10[c * 4 + 0], w.x, a0);
      a1 = fmaf(h10[c * 4 + 1], w.y, a1);
      a0 = fmaf(h10[c * 4 + 2], w.z, a0);
      a1 = fmaf(h10[c * 4 + 3], w.w, a1);
      c0 = fmaf(h11[c * 4 + 0], w.x, c0);
      c1 = fmaf(h11[c * 4 + 1], w.y, c1);
      c0 = fmaf(h11[c * 4 + 2], w.z, c0);
      c1 = fmaf(h11[c * 4 + 3], w.w, c1);
    }
    const float s0 = a0 + a1, s1 = c0 + c1;   // partials for e0, e1
    float u = hi ? s1 : s0;                   // own-entry partial
    float v = hi ? s0 : s1;                   // partner-entry partial
    u = DPP_ADD(u, v, ROW_ROR8);  // lanes p<8 hold e0-partials, p>=8 e1
    u = DPP_ADD(u, u, ROW_SHR1);
    u = DPP_ADD(u, u, ROW_SHR2);
    u = DPP_ADD(u, u, ROW_SHR4);  // full sum at p==7 / p==15
    const float h2 = fmaxf(u + b2[j], 0.0f);
    y = fmaf(h2, W3[j], y);
  }
  if ((p & 7) == 7) table[e0 + (p >> 3)] = y + b3v;
}

// ---------------- kS: scan + lookback + epilogue ----------------
__global__ __launch_bounds__(TPB) void kS(const float* __restrict__ x, int n,
                                          const float* __restrict__ table,
                                          unsigned int* __restrict__ gsum,
                                          unsigned int* __restrict__ gticket,
                                          float* __restrict__ out) {
  __shared__ int swl[4], swc[4];
  __shared__ int sgx;
  const int t = threadIdx.x, b = blockIdx.x;
  const int lane = t & 63, wv = t >> 6;
  const int base = b * CHUNK + t * ITEMS;

  // ---- chunk load + thread-local mask ----
  float xs[ITEMS];
  const bool full = (base + ITEMS) <= n;
  if (full) {
    const float2 v = *(const float2*)(x + base);
    xs[0] = v.x; xs[1] = v.y;
  } else {
    #pragma unroll
    for (int it = 0; it < ITEMS; ++it)
      xs[it] = (base + it < n) ? x[base + it] : 0.0f;
  }
  float prev = (base > 0 && base <= n) ? x[base - 1] : 0.0f;
  unsigned m = 0; int tl = -1; int cnt = 0;
  #pragma unroll
  for (int it = 0; it < ITEMS; ++it) {
    const int i = base + it;
    if (i < n) {
      const bool act = (i == 0) || (fabsf(xs[it] - prev) > THRESH);
      if (act) { tl = i; ++cnt; m |= (1u << it); }
      prev = xs[it];
    }
  }

  // ---- wave scans ----
  int incl = tl;
  #pragma unroll
  for (int off = 1; off < 64; off <<= 1) {
    const int v = __shfl_up(incl, off);
    if (lane >= off) incl = max(incl, v);
  }
  int wsum = cnt;
  #pragma unroll
  for (int off = 1; off < 64; off <<= 1) wsum += __shfl_xor(wsum, off);
  if (lane == 63) swl[wv] = incl;
  if (lane == 0)  swc[wv] = wsum;

  // ---- wave 0: exact backward lookback for block prefix ----
  if (wv == 0) {
    int g = -1;
    if (b > 0) {
      int ws = b * CHUNK - 64;
      for (;;) {
        const int i = ws + lane;
        const float xi = x[i];
        const float xp = (i > 0) ? x[i - 1] : 0.0f;
        const bool act = (i == 0) || (fabsf(xi - xp) > THRESH);
        const unsigned long long bal = __ballot(act);
        if (bal) { g = ws + 63 - (int)__builtin_clzll(bal); break; }
        ws -= 64;   // terminates: element 0 forced active
      }
    }
    if (lane == 0) sgx = g;
  }
  __syncthreads();

  // ---- combine: run start for this thread ----
  const int exclW = __shfl_up(incl, 1);
  int run = sgx;
  #pragma unroll
  for (int w = 0; w < 4; ++w) if (w < wv) run = max(run, swl[w]);
  if (lane > 0) run = max(run, exclW);

  // ---- publish n_active: banked adds + ticket (poison-bias encoding) ----
  bool winner = false;
  if (t == 0) {
    const unsigned bcnt = (unsigned)(swc[0] + swc[1] + swc[2] + swc[3]);
    __hip_atomic_fetch_add(&gsum[(b & 15) * 16], bcnt,
                           __ATOMIC_RELAXED, __HIP_MEMORY_SCOPE_AGENT);
    const unsigned tk = __hip_atomic_fetch_add(gticket, 1u,
                                               __ATOMIC_ACQ_REL,
                                               __HIP_MEMORY_SCOPE_AGENT);
    winner = (tk == POISON32 + (unsigned)(NSCAN - 1));
  }

  // ---- epilogue: lerp + decay (normal cached loads) ----
  const float invstep = (float)(TSZ - 1) / (GMAX - GMIN);
  if (full) {
    float o[ITEMS];
    #pragma unroll
    for (int it = 0; it < ITEMS; ++it) {
      const int i = base + it;
      const bool act = (m >> it) & 1u;
      if (act) run = i;
      const float xj = act ? xs[it] : x[run];
      const float u = (xj - GMIN) * invstep;
      int i0 = (int)u;
      i0 = max(0, min(i0, TSZ - 2));
      const float f = u - (float)i0;
      const float t0 = table[i0], t1 = table[i0 + 1];
      o[it] = fmaf(f, t1 - t0, t0) * __expf((float)(run - i) * 0.05f);
    }
    float2 ov = { o[0], o[1] };
    *(float2*)(out + base) = ov;
  } else {
    #pragma unroll
    for (int it = 0; it < ITEMS; ++it) {
      const int i = base + it;
      if (i >= n) break;
      const bool act = (m >> it) & 1u;
      if (act) run = i;
      const float xj = act ? xs[it] : x[run];
      const float u = (xj - GMIN) * invstep;
      int i0 = (int)u;
      i0 = max(0, min(i0, TSZ - 2));
      const float f = u - (float)i0;
      const float t0 = table[i0], t1 = table[i0 + 1];
      out[i] = fmaf(f, t1 - t0, t0) * __expf((float)(run - i) * 0.05f);
    }
  }

  // ---- last-arriving block: fold banks, write n_active ----
  if (winner) {
    unsigned s = 0;
    #pragma unroll
    for (int k = 0; k < 16; ++k)
      s += __hip_atomic_load(&gsum[k * 16], __ATOMIC_RELAXED,
                             __HIP_MEMORY_SCOPE_AGENT);
    s -= 16u * POISON32;   // remove poison bias (mod-2^32 exact)
    out[n] = (float)(int)s;
  }
}

extern "C" void kernel_launch(void* const* d_in, const int* in_sizes, int n_in,
                              void* d_out, int out_size, void* d_ws, size_t ws_size,
                              hipStream_t stream) {
  const float* x  = (const float*)d_in[0];
  const float* W1 = (const float*)d_in[1];
  const float* b1 = (const float*)d_in[2];
  const float* W2 = (const float*)d_in[3];
  const float* b2 = (const float*)d_in[4];
  const float* W3 = (const float*)d_in[5];
  const float* b3 = (const float*)d_in[6];
  float* out = (float*)d_out;
  const int n = in_sizes[0];                   // 1048576 = NSCAN * CHUNK

  char* w = (char*)d_ws;
  float* table = (float*)w;                               // 32 KB
  unsigned int* gsum    = (unsigned int*)(w + TSZ * 4);   // 16 banks x 64B
  unsigned int* gticket = (unsigned int*)(w + TSZ * 4 + 1024);

  kT<<<NTBLK, TPB, 0, stream>>>(W1, b1, W2, b2, W3, b3, table);
  kS<<<NSCAN, TPB, 0, stream>>>(x, n, table, gsum, gticket, out);
}

// Round 11
// 91.412 us; speedup vs baseline: 1.3620x; 1.3620x over previous
//
#include <hip/hip_runtime.h>
#include <math.h>

// AetherSparcNet round 11 — REVERT to round-8 champion (90.4us), verbatim.
// Ten-round evidence: the R8 structure is the only one that works on this
// chip. Agent-scope sync stronger than relaxed self-contained stores
// (acquire fences R4, bypass-load chains R6, mass mailbox polling R9,
// per-block ACQ_REL ticket R10) costs 25-50us: agent acquire invalidates
// the per-XCD L1+L2 (coherence point is below L2 on 8-XCD MI355X).
//   kT: 256 blocks x 256 thr, 32 entries/block (s=16 lane k-split, E=2
//       entries/group, merged dual-entry butterfly w/ 4 shfl). W2 staged
//       in LDS. Plain table stores; kernel boundary publishes to kS.
//   kS: 2048 blocks x 256 thr x ITEMS=2 (CHUNK=512) -> thin blocks, warm
//       caches, no fences. Exact backward lookback for block prefix (mask
//       ~97.5% dense -> expected 1 iter; i=0 forced active terminates).
//       cnts published as self-contained relaxed agent stores (+1
//       encoding, 0xAA poison = not-ready); block 0 alone gathers the
//       2048 slots -> out[n] = n_active (fp32).

#define THRESH   0.045f
#define NH       128
#define TSZ      8192
#define GMIN     -6.0f
#define GMAX     6.0f
#define TPB      256
#define ITEMS    2
#define CHUNK    (TPB * ITEMS)   // 512
#define NSCAN    2048            // 1M / 512
#define NTBLK    256             // table blocks, 32 entries each
#define POISON32 0xAAAAAAAAu

// ---------------- kT: table build (s=16, E=2) ----------------
__global__ __launch_bounds__(TPB) void kT(const float* __restrict__ W1,
                                          const float* __restrict__ b1,
                                          const float* __restrict__ W2,
                                          const float* __restrict__ b2,
                                          const float* __restrict__ W3,
                                          const float* __restrict__ b3,
                                          float* __restrict__ table) {
  __shared__ float w2s[NH * NH];  // 64 KB
  const int t = threadIdx.x, b = blockIdx.x;
  {
    const float4* src = (const float4*)W2;
    float4* dst = (float4*)w2s;
    #pragma unroll
    for (int i = 0; i < (NH * NH / 4) / TPB; ++i)   // 16 iters
      dst[t + i * TPB] = src[t + i * TPB];
  }
  __syncthreads();

  const int p  = t & 15;                  // lane in 16-lane group
  const int e0 = b * 32 + (t >> 4) * 2;   // 16 groups x 2 entries
  const float step = (GMAX - GMIN) * (1.0f / (float)(TSZ - 1));
  const float xv0 = GMIN + step * (float)e0;
  const float xv1 = xv0 + step;

  // lane p owns k in {4*(p+16c)+r : c<2, r<4}  (16 lanes x 8 = 128)
  float h10[8], h11[8];
  #pragma unroll
  for (int c = 0; c < 2; ++c) {
    #pragma unroll
    for (int r = 0; r < 4; ++r) {
      const int k = 4 * (p + 16 * c) + r;
      const float w = W1[k], bb = b1[k];
      h10[c * 4 + r] = fmaxf(fmaf(xv0, w, bb), 0.0f);
      h11[c * 4 + r] = fmaxf(fmaf(xv1, w, bb), 0.0f);
    }
  }
  const bool hi = (p & 8) != 0;
  float y = 0.0f;                 // lo half-group accumulates e0, hi e1
  const float b3v = b3[0];
  #pragma unroll 4
  for (int j = 0; j < NH; ++j) {
    const float* row = &w2s[j * NH];
    float a0 = 0.f, a1 = 0.f, c0 = 0.f, c1 = 0.f;
    #pragma unroll
    for (int c = 0; c < 2; ++c) {
      const float4 w = *(const float4*)&row[4 * (p + 16 * c)];
      a0 = fmaf(h10[c * 4 + 0], w.x, a0);
      a1 = fmaf(h10[c * 4 + 1], w.y, a1);
      a0 = fmaf(h10[c * 4 + 2], w.z, a0);
      a1 = fmaf(h10[c * 4 + 3], w.w, a1);
      c0 = fmaf(h11[c * 4 + 0], w.x, c0);
      c1 = fmaf(h11[c * 4 + 1], w.y, c1);
      c0 = fmaf(h11[c * 4 + 2], w.z, c0);
      c1 = fmaf(h11[c * 4 + 3], w.w, c1);
    }
    const float s0 = a0 + a1, s1 = c0 + c1;   // partials for e0, e1
    float u = hi ? s1 : s0;                    // own entry
    float v = hi ? s0 : s1;                    // partner entry
    v = __shfl_xor(v, 8);
    u += v;                                    // e-partial over {p, p^8}
    u += __shfl_xor(u, 1);
    u += __shfl_xor(u, 2);
    u += __shfl_xor(u, 4);                     // full sum in each half-group
    const float h2 = fmaxf(u + b2[j], 0.0f);
    y = fmaf(h2, W3[j], y);
  }
  if ((p & 7) == 0) table[e0 + (p >> 3)] = y + b3v;
}

// ---------------- kS: scan + lookback + epilogue ----------------
__global__ __launch_bounds__(TPB) void kS(const float* __restrict__ x, int n,
                                          const float* __restrict__ table,
                                          unsigned int* __restrict__ cnts,
                                          float* __restrict__ out) {
  __shared__ int swl[4], swc[4], sred[4];
  __shared__ int sgx;
  const int t = threadIdx.x, b = blockIdx.x;
  const int lane = t & 63, wv = t >> 6;
  const int base = b * CHUNK + t * ITEMS;

  // ---- chunk load + thread-local mask ----
  float xs[ITEMS];
  const bool full = (base + ITEMS) <= n;
  if (full) {
    const float2 v = *(const float2*)(x + base);
    xs[0] = v.x; xs[1] = v.y;
  } else {
    #pragma unroll
    for (int it = 0; it < ITEMS; ++it)
      xs[it] = (base + it < n) ? x[base + it] : 0.0f;
  }
  float prev = (base > 0 && base <= n) ? x[base - 1] : 0.0f;
  unsigned m = 0; int tl = -1; int cnt = 0;
  #pragma unroll
  for (int it = 0; it < ITEMS; ++it) {
    const int i = base + it;
    if (i < n) {
      const bool act = (i == 0) || (fabsf(xs[it] - prev) > THRESH);
      if (act) { tl = i; ++cnt; m |= (1u << it); }
      prev = xs[it];
    }
  }

  // ---- wave scans ----
  int incl = tl;
  #pragma unroll
  for (int off = 1; off < 64; off <<= 1) {
    const int v = __shfl_up(incl, off);
    if (lane >= off) incl = max(incl, v);
  }
  int wsum = cnt;
  #pragma unroll
  for (int off = 1; off < 64; off <<= 1) wsum += __shfl_xor(wsum, off);
  if (lane == 63) swl[wv] = incl;
  if (lane == 0)  swc[wv] = wsum;

  // ---- wave 0: exact backward lookback for block prefix ----
  if (wv == 0) {
    int g = -1;
    if (b > 0) {
      int ws = b * CHUNK - 64;
      for (;;) {
        const int i = ws + lane;
        const float xi = x[i];
        const float xp = (i > 0) ? x[i - 1] : 0.0f;
        const bool act = (i == 0) || (fabsf(xi - xp) > THRESH);
        const unsigned long long bal = __ballot(act);
        if (bal) { g = ws + 63 - (int)__builtin_clzll(bal); break; }
        ws -= 64;   // terminates: element 0 forced active
      }
    }
    if (lane == 0) sgx = g;
  }
  __syncthreads();

  // ---- combine: run start for this thread ----
  const int exclW = __shfl_up(incl, 1);
  int run = sgx;
  #pragma unroll
  for (int w = 0; w < 4; ++w) if (w < wv) run = max(run, swl[w]);
  if (lane > 0) run = max(run, exclW);

  // ---- publish block count (self-contained; relaxed agent) ----
  if (t == 0) {
    const int bcnt = swc[0] + swc[1] + swc[2] + swc[3];
    __hip_atomic_store(&cnts[b], (unsigned)(bcnt + 1),
                       __ATOMIC_RELAXED, __HIP_MEMORY_SCOPE_AGENT);
  }

  // ---- epilogue: lerp + decay (normal cached loads) ----
  const float invstep = (float)(TSZ - 1) / (GMAX - GMIN);
  if (full) {
    float o[ITEMS];
    #pragma unroll
    for (int it = 0; it < ITEMS; ++it) {
      const int i = base + it;
      const bool act = (m >> it) & 1u;
      if (act) run = i;
      const float xj = act ? xs[it] : x[run];
      const float u = (xj - GMIN) * invstep;
      int i0 = (int)u;
      i0 = max(0, min(i0, TSZ - 2));
      const float f = u - (float)i0;
      const float t0 = table[i0], t1 = table[i0 + 1];
      o[it] = fmaf(f, t1 - t0, t0) * __expf((float)(run - i) * 0.05f);
    }
    float2 ov = { o[0], o[1] };
    *(float2*)(out + base) = ov;
  } else {
    #pragma unroll
    for (int it = 0; it < ITEMS; ++it) {
      const int i = base + it;
      if (i >= n) break;
      const bool act = (m >> it) & 1u;
      if (act) run = i;
      const float xj = act ? xs[it] : x[run];
      const float u = (xj - GMIN) * invstep;
      int i0 = (int)u;
      i0 = max(0, min(i0, TSZ - 2));
      const float f = u - (float)i0;
      const float t0 = table[i0], t1 = table[i0 + 1];
      out[i] = fmaf(f, t1 - t0, t0) * __expf((float)(run - i) * 0.05f);
    }
  }

  // ---- block 0 only: gather n_active (no other block waits) ----
  if (b == 0) {
    int v = 0;
    #pragma unroll
    for (int s8 = 0; s8 < NSCAN / TPB; ++s8) {   // 8 slots/thread
      const int idx = t + s8 * TPB;
      unsigned c;
      for (;;) {
        c = __hip_atomic_load(&cnts[idx], __ATOMIC_RELAXED,
                              __HIP_MEMORY_SCOPE_AGENT);
        if (c != POISON32) break;
        __builtin_amdgcn_s_sleep(1);
      }
      v += (int)c - 1;
    }
    #pragma unroll
    for (int off = 1; off < 64; off <<= 1) v += __shfl_xor(v, off);
    if (lane == 0) sred[wv] = v;
    __syncthreads();
    if (t == 0) out[n] = (float)(sred[0] + sred[1] + sred[2] + sred[3]);
  }
}

extern "C" void kernel_launch(void* const* d_in, const int* in_sizes, int n_in,
                              void* d_out, int out_size, void* d_ws, size_t ws_size,
                              hipStream_t stream) {
  const float* x  = (const float*)d_in[0];
  const float* W1 = (const float*)d_in[1];
  const float* b1 = (const float*)d_in[2];
  const float* W2 = (const float*)d_in[3];
  const float* b2 = (const float*)d_in[4];
  const float* W3 = (const float*)d_in[5];
  const float* b3 = (const float*)d_in[6];
  float* out = (float*)d_out;
  const int n = in_sizes[0];                   // 1048576 = NSCAN * CHUNK

  char* w = (char*)d_ws;
  float* table = (float*)w;                               // 32 KB
  unsigned int* cnts = (unsigned int*)(w + TSZ * 4);      // 8 KB

  kT<<<NTBLK, TPB, 0, stream>>>(W1, b1, W2, b2, W3, b3, table);
  kS<<<NSCAN, TPB, 0, stream>>>(x, n, table, cnts, out);
}